// Round 1
// baseline (156.949 us; speedup 1.0000x reference)
//
#include <hip/hip_runtime.h>

#define S_LEN 2048
#define D_MODEL 1024
#define NB 4

typedef unsigned short u16;
typedef __attribute__((ext_vector_type(8))) short short8;
typedef __attribute__((ext_vector_type(4))) float f32x4;
typedef __attribute__((ext_vector_type(4))) unsigned short u16x4;

__device__ inline u16 f2bf(float f) {
  union { float f; unsigned u; } v; v.f = f;
  unsigned u = v.u;
  unsigned r = (u + 0x7FFFu + ((u >> 16) & 1u)) >> 16;
  return (u16)r;
}

__device__ inline void glds16(const void* g, void* l) {
  __builtin_amdgcn_global_load_lds((const __attribute__((address_space(1))) void*)g,
                                   (__attribute__((address_space(3))) void*)l,
                                   16, 0, 0);
}

// ---------------- LayerNorm (fp32 in -> bf16 out) ----------------
__global__ __launch_bounds__(256) void ln_kernel(const float* __restrict__ ctx,
                                                 const float* __restrict__ gamma,
                                                 const float* __restrict__ beta,
                                                 u16* __restrict__ xb) {
  const int row = blockIdx.x;
  const int t = threadIdx.x;
  const f32x4 v = ((const f32x4*)(ctx + (size_t)row * D_MODEL))[t];
  float s = v[0] + v[1] + v[2] + v[3];
  float q = v[0]*v[0] + v[1]*v[1] + v[2]*v[2] + v[3]*v[3];
  for (int o = 32; o > 0; o >>= 1) { s += __shfl_xor(s, o); q += __shfl_xor(q, o); }
  __shared__ float rs[4], rq[4];
  const int wave = t >> 6, lane = t & 63;
  if (lane == 0) { rs[wave] = s; rq[wave] = q; }
  __syncthreads();
  s = rs[0] + rs[1] + rs[2] + rs[3];
  q = rq[0] + rq[1] + rq[2] + rq[3];
  const float mu = s * (1.0f / D_MODEL);
  const float var = q * (1.0f / D_MODEL) - mu * mu;
  const float rstd = rsqrtf(var + 1e-3f);
  const f32x4 g4 = ((const f32x4*)gamma)[t];
  const f32x4 b4 = ((const f32x4*)beta)[t];
  u16x4 o;
  o[0] = f2bf((v[0] - mu) * rstd * g4[0] + b4[0]);
  o[1] = f2bf((v[1] - mu) * rstd * g4[1] + b4[1]);
  o[2] = f2bf((v[2] - mu) * rstd * g4[2] + b4[2]);
  o[3] = f2bf((v[3] - mu) * rstd * g4[3] + b4[3]);
  ((u16x4*)(xb + (size_t)row * D_MODEL))[t] = o;
}

// ---------------- weight prep: Wt[n][k] = bf16(W[k][n]), n: [Wq cols | Wk cols] ----------------
__global__ __launch_bounds__(256) void prep_w(const float* __restrict__ Wq,
                                              const float* __restrict__ Wk,
                                              u16* __restrict__ Wt) {
  __shared__ float tile[32][33];
  const int k0 = blockIdx.x * 32;
  const int n0 = blockIdx.y * 32;
  const int tx = threadIdx.x, ty = threadIdx.y;
  const float* W = (n0 < D_MODEL) ? Wq : Wk;
  const int nl0 = (n0 < D_MODEL) ? n0 : (n0 - D_MODEL);
  #pragma unroll
  for (int j = 0; j < 32; j += 8)
    tile[ty + j][tx] = W[(size_t)(k0 + ty + j) * D_MODEL + nl0 + tx];
  __syncthreads();
  #pragma unroll
  for (int j = 0; j < 32; j += 8)
    Wt[(size_t)(n0 + ty + j) * D_MODEL + k0 + tx] = f2bf(tile[tx][ty + j]);
}

__global__ __launch_bounds__(256) void prep_bias(const float* __restrict__ bq,
                                                 const float* __restrict__ bk,
                                                 float* __restrict__ biasQK) {
  const int n = blockIdx.x * 256 + threadIdx.x;
  biasQK[n] = (n < D_MODEL) ? bq[n] : bk[n - D_MODEL];
}

// ---------------- bf16 GEMM: C[m][n] = sum_k A[m][k]*Bt[n][k]  (m97-style 128x128 tile) ----------------
// MODE 0: C = bf16, += bias[n].   MODE 1: C = fp32, *= scale.
template <int MODE>
__global__ __launch_bounds__(256, 2) void gemm_bt(
    const u16* __restrict__ A, int lda, long long strideA,
    const u16* __restrict__ Bt, int ldb, long long strideB,
    void* __restrict__ Cout, int ldc, long long strideC,
    const float* __restrict__ bias, float scale, int K) {
  __shared__ u16 As[128][32];
  __shared__ u16 Bs[128][32];
  const int tid = threadIdx.x;
  const int wave = tid >> 6, lane = tid & 63;
  const int z = blockIdx.z;
  A += (size_t)z * strideA;
  Bt += (size_t)z * strideB;
  const size_t m0 = (size_t)blockIdx.y * 128;
  const size_t n0 = (size_t)blockIdx.x * 128;
  const int wr = (wave >> 1) * 64;
  const int wc = (wave & 1) * 64;
  const int strow = wave * 16 + (lane >> 2);   // staging row within tile (call 0)
  const int stslot = (lane & 3) * 8;           // staging k element offset
  const int fr = lane & 15, fq = lane >> 4;

  f32x4 acc[4][4];
  #pragma unroll
  for (int i = 0; i < 4; ++i)
    #pragma unroll
    for (int j = 0; j < 4; ++j) acc[i][j] = (f32x4)(0.0f);

  for (int k0 = 0; k0 < K; k0 += 32) {
    const u16* ga = A + (m0 + strow) * lda + k0 + stslot;
    const u16* gb = Bt + (n0 + strow) * ldb + k0 + stslot;
    glds16(ga, &As[wave * 16][0]);
    glds16(ga + (size_t)64 * lda, &As[64 + wave * 16][0]);
    glds16(gb, &Bs[wave * 16][0]);
    glds16(gb + (size_t)64 * ldb, &Bs[64 + wave * 16][0]);
    __syncthreads();
    short8 af[4], bfv[4];
    #pragma unroll
    for (int mi = 0; mi < 4; ++mi) af[mi] = *(const short8*)&As[wr + mi * 16 + fr][fq * 8];
    #pragma unroll
    for (int ni = 0; ni < 4; ++ni) bfv[ni] = *(const short8*)&Bs[wc + ni * 16 + fr][fq * 8];
    #pragma unroll
    for (int mi = 0; mi < 4; ++mi)
      #pragma unroll
      for (int ni = 0; ni < 4; ++ni)
        acc[mi][ni] = __builtin_amdgcn_mfma_f32_16x16x32_bf16(af[mi], bfv[ni], acc[mi][ni], 0, 0, 0);
    __syncthreads();
  }

  if (MODE == 0) {
    u16* C = (u16*)Cout + (size_t)z * strideC;
    #pragma unroll
    for (int mi = 0; mi < 4; ++mi)
      #pragma unroll
      for (int ni = 0; ni < 4; ++ni) {
        const size_t row = m0 + wr + mi * 16 + fq * 4;
        const size_t col = n0 + wc + ni * 16 + fr;
        const float bb = bias[col];
        #pragma unroll
        for (int r = 0; r < 4; ++r)
          C[(row + r) * ldc + col] = f2bf(acc[mi][ni][r] + bb);
      }
  } else {
    float* C = (float*)Cout + (size_t)z * strideC;
    #pragma unroll
    for (int mi = 0; mi < 4; ++mi)
      #pragma unroll
      for (int ni = 0; ni < 4; ++ni) {
        const size_t row = m0 + wr + mi * 16 + fq * 4;
        const size_t col = n0 + wc + ni * 16 + fr;
        #pragma unroll
        for (int r = 0; r < 4; ++r)
          C[(row + r) * ldc + col] = acc[mi][ni][r] * scale;
      }
  }
}

// ---------------- row softmax + prior transform ----------------
__global__ __launch_bounds__(256) void softmax_kernel(const float* __restrict__ scores,
                                                      float* __restrict__ na,
                                                      const float* __restrict__ prior) {
  const int row = blockIdx.x;
  const int t = threadIdx.x;
  const f32x4* srow = (const f32x4*)(scores + (size_t)row * S_LEN);
  const f32x4 v0 = srow[t];
  const f32x4 v1 = srow[t + 256];
  float mx = fmaxf(fmaxf(fmaxf(v0[0], v0[1]), fmaxf(v0[2], v0[3])),
                   fmaxf(fmaxf(v1[0], v1[1]), fmaxf(v1[2], v1[3])));
  for (int o = 32; o > 0; o >>= 1) mx = fmaxf(mx, __shfl_xor(mx, o));
  __shared__ float red[4];
  __shared__ float red2[4];
  const int wave = t >> 6, lane = t & 63;
  if (lane == 0) red[wave] = mx;
  __syncthreads();
  mx = fmaxf(fmaxf(red[0], red[1]), fmaxf(red[2], red[3]));
  float e[8];
  #pragma unroll
  for (int u = 0; u < 4; ++u) e[u] = __expf(v0[u] - mx);
  #pragma unroll
  for (int u = 0; u < 4; ++u) e[4 + u] = __expf(v1[u] - mx);
  float s = 0.0f;
  #pragma unroll
  for (int u = 0; u < 8; ++u) s += e[u];
  for (int o = 32; o > 0; o >>= 1) s += __shfl_xor(s, o);
  if (lane == 0) red2[wave] = s;
  __syncthreads();
  s = red2[0] + red2[1] + red2[2] + red2[3];
  const float pr = prior[0];
  const float w = 1.0f - pr;
  const float inv = 1.0f / s;
  f32x4 o0, o1;
  #pragma unroll
  for (int u = 0; u < 4; ++u) o0[u] = pr + w * (e[u] * inv + 1e-9f);
  #pragma unroll
  for (int u = 0; u < 4; ++u) o1[u] = pr + w * (e[4 + u] * inv + 1e-9f);
  f32x4* nrow = (f32x4*)(na + (size_t)row * S_LEN);
  nrow[t] = o0;
  nrow[t + 256] = o1;
}

// ---------------- gather diag+superdiag, log, prefix scan ----------------
__global__ __launch_bounds__(256) void scan_kernel(const float* __restrict__ na,
                                                   float* __restrict__ Cpre,
                                                   float* __restrict__ diag) {
  const int b = blockIdx.x, t = threadIdx.x;
  const float* nb = na + (size_t)b * S_LEN * S_LEN;
  float loc[8];
  float tot = 0.0f;
  #pragma unroll
  for (int u = 0; u < 8; ++u) {
    const int i = t * 8 + u;
    diag[b * S_LEN + i] = nb[(size_t)i * S_LEN + i];
    float e = 0.0f;
    if (i < S_LEN - 1) e = logf(nb[(size_t)i * S_LEN + i + 1] + 1e-9f);
    loc[u] = tot;
    tot += e;
  }
  __shared__ float sbuf[256];
  sbuf[t] = tot;
  __syncthreads();
  for (int off = 1; off < 256; off <<= 1) {
    const float v = (t >= off) ? sbuf[t - off] : 0.0f;
    __syncthreads();
    sbuf[t] += v;
    __syncthreads();
  }
  const float base = (t == 0) ? 0.0f : sbuf[t - 1];
  #pragma unroll
  for (int u = 0; u < 8; ++u)
    Cpre[b * S_LEN + t * 8 + u] = base + loc[u];
}

// ---------------- g_attn: exp(C[max]-C[min]) + 1e-9, diag from na ----------------
__global__ __launch_bounds__(256) void gattn_kernel(const float* __restrict__ Cpre,
                                                    const float* __restrict__ diag,
                                                    float* __restrict__ g) {
  const int b = blockIdx.z, i = blockIdx.y;
  const int j0 = blockIdx.x * 1024 + threadIdx.x * 4;
  const float Ci = Cpre[b * S_LEN + i];
  const float di = diag[b * S_LEN + i];
  const f32x4 Cj = *(const f32x4*)&Cpre[b * S_LEN + j0];
  f32x4 o;
  #pragma unroll
  for (int u = 0; u < 4; ++u) {
    const int j = j0 + u;
    const float arg = (j > i) ? (Cj[u] - Ci) : (Ci - Cj[u]);
    o[u] = (j == i) ? (di + 1e-9f) : (__expf(arg) + 1e-9f);
  }
  *(f32x4*)(g + ((size_t)b * S_LEN + i) * S_LEN + j0) = o;
}

extern "C" void kernel_launch(void* const* d_in, const int* in_sizes, int n_in,
                              void* d_out, int out_size, void* d_ws, size_t ws_size,
                              hipStream_t stream) {
  const float* ctx   = (const float*)d_in[0];
  // d_in[1] = eos_mask: numerically a no-op (mask * 1e-19 in fp32), never read.
  const float* prior = (const float*)d_in[2];
  const float* gamma = (const float*)d_in[3];
  const float* beta  = (const float*)d_in[4];
  const float* Wk    = (const float*)d_in[5];
  const float* bk    = (const float*)d_in[6];
  const float* Wq    = (const float*)d_in[7];
  const float* bq    = (const float*)d_in[8];

  float* g  = (float*)d_out;                               // g_attn region (also scores scratch)
  float* na = g + (size_t)NB * S_LEN * S_LEN;              // neibor_attn region

  // scratch inside the na output region (overwritten by softmax later):
  u16* Xb  = (u16*)na;                                     // [8192][1024] bf16 (16 MiB)
  u16* QKb = (u16*)na + (size_t)(NB * S_LEN) * D_MODEL;    // [8192][2048] bf16 (32 MiB)
  // small scratch in ws:
  u16*   Wt     = (u16*)d_ws;                              // [2048][1024] bf16 (4 MiB)
  float* biasQK = (float*)((char*)d_ws + (size_t)2048 * 1024 * 2);
  float* Cpre   = biasQK + 2048;
  float* diag   = Cpre + NB * S_LEN;

  ln_kernel<<<NB * S_LEN, 256, 0, stream>>>(ctx, gamma, beta, Xb);
  prep_w<<<dim3(32, 64), dim3(32, 8), 0, stream>>>(Wq, Wk, Wt);
  prep_bias<<<8, 256, 0, stream>>>(bq, bk, biasQK);

  // [q|k] = Xn @ [Wq|Wk] + [bq|bk], output bf16
  gemm_bt<0><<<dim3(16, 64, 1), 256, 0, stream>>>(Xb, D_MODEL, 0,
                                                  Wt, D_MODEL, 0,
                                                  QKb, 2 * D_MODEL, 0,
                                                  biasQK, 1.0f, D_MODEL);
  // scores[b] = q[b] @ k[b]^T / d_model, fp32, into g region
  gemm_bt<1><<<dim3(16, 16, NB), 256, 0, stream>>>(QKb, 2 * D_MODEL, (long long)S_LEN * 2 * D_MODEL,
                                                   QKb + D_MODEL, 2 * D_MODEL, (long long)S_LEN * 2 * D_MODEL,
                                                   g, S_LEN, (long long)S_LEN * S_LEN,
                                                   nullptr, 1.0f / (float)D_MODEL, D_MODEL);

  softmax_kernel<<<NB * S_LEN, 256, 0, stream>>>(g, na, prior);
  scan_kernel<<<NB, 256, 0, stream>>>(na, Cpre, diag);
  gattn_kernel<<<dim3(2, S_LEN, NB), 256, 0, stream>>>(Cpre, diag, g);
}